// Round 5
// baseline (214.747 us; speedup 1.0000x reference)
//
#include <hip/hip_runtime.h>

typedef __bf16 bf16x4 __attribute__((ext_vector_type(4)));
typedef __bf16 bf16x8 __attribute__((ext_vector_type(8)));
typedef float f32x16 __attribute__((ext_vector_type(16)));

#define TC 2.885390081777926f   // 2/ln2, folded into W0/W1 at prep

// ---- workspace layout (bf16 element offsets), FRAGMENT-ORDERED weights ----
// 1 KB record per (nt,kk): elem (lane,j) at rec*512 + lane*8 + j
//   n = nt*32 + (lane&31), k = kk*16 + (lane>>5)*8 + j
#define W0F_OFF 0                 // 16 recs
#define W1F_OFF 8192              // 512 recs
#define W2F_OFF (8192 + 262144)   // 160 recs (n>=136 zero)

// One wave per 1KB record: coalesced row reads, coalesced dwordx4 stores.
// W0/W1 pre-scaled by TC (tanh exp2 scale).
__global__ void prep_weights(const float* __restrict__ W0,
                             const float* __restrict__ W1,
                             const float* __restrict__ W2,
                             __bf16* __restrict__ ws) {
    const int wave = blockIdx.x * 8 + (threadIdx.x >> 6);   // 0..687
    const int l   = threadIdx.x & 63;
    const int col = l & 31, kh = l >> 5;
    const float* src; int nt, kk, S, nlim; float scl;
    if (wave < 16)       { src = W0; nt = wave; kk = 0;      S = 512; nlim = 512; scl = TC; }
    else if (wave < 528) { int r = wave - 16;  src = W1; nt = r >> 5; kk = r & 31; S = 512; nlim = 512; scl = TC; }
    else                 { int r = wave - 528; src = W2; nt = r >> 5; kk = r & 31; S = 136; nlim = 136; scl = 1.0f; }
    const int n  = nt * 32 + col;
    const int k0 = kk * 16 + kh * 8;
    bf16x8 v;
#pragma unroll
    for (int j = 0; j < 8; ++j)
        v[j] = (n < nlim) ? (__bf16)(src[(k0 + j) * S + n] * scl) : (__bf16)0.0f;
    *(bf16x8*)(ws + wave * 512 + l * 8) = v;
}

// input y is pre-scaled by TC: tanh(x) = 1 - 2/(exp2(TC*x)+1)
__device__ __forceinline__ float fast_tanh_pre(float y) {
#if __has_builtin(__builtin_amdgcn_exp2f)
    float e = __builtin_amdgcn_exp2f(y);
#else
    float e = exp2f(y);
#endif
    return 1.0f - 2.0f * __builtin_amdgcn_rcpf(e + 1.0f);
}

#define HSTR 520
#define NSTR 140

// R22: SLIM ANTI-PHASE. R20/R21 both spilled (WRITE_SIZE 10/48 MB) because
// macro temporaries pushed arch-VGPR demand past 128 while 128 acc AGPRs were
// pinned (256-reg cap @ 2 waves/SIMD). The mechanism (m114: each SIMD hosts
// one MFMA-mode + one VALU-mode wave; anti-phased partner's VALU fills the
// correlated load-stall cycles that same-phase partners cannot) was never
// cleanly tested. R22 slims every body: P2M 2-deep (<=24 VGPR, was 64; also
// E-tile shares A rows with main tile for w<2 -> 8 fewer ds_reads/iter),
// PH0 single f32x16 temp, P1M verbatim R17. Peak (S2, w<4 path):
// 128 AGPR + ~32 buf + ~12 epi + ~15 addr ~= 190 < 256.
// TRIPWIRE: WRITE_SIZE ~512 KB / FETCH ~7 MB, else spilled again -> abandon.
__global__ __launch_bounds__(512, 2)
void fused_mlp_quad(const float* __restrict__ points,
                    const float* __restrict__ b0,
                    const float* __restrict__ b1,
                    const float* __restrict__ b2,
                    const __bf16* __restrict__ ws,
                    float* __restrict__ out) {
    __shared__ __align__(16) unsigned char lds_raw[133120];
    __bf16* h  = (__bf16*)lds_raw;   // [128][HSTR] bf16
    float* net = (float*)lds_raw;    // [128][NSTR] f32 overlay (liveness staggered)

    const __bf16* w0f = ws + W0F_OFF;
    const __bf16* w1f = ws + W1F_OFF;
    const __bf16* w2f = ws + W2F_OFF;

    const int tid = threadIdx.x;
    const int w   = tid >> 6;
    const int l   = tid & 63;
    const int ln  = l & 31;
    const int hi  = l >> 5;
    const int row0 = blockIdx.x * 128;

    const int lofs = l * 8;
    const int ofs16 = (blockIdx.x >> 3) & 15;
    const int ofs8  = (blockIdx.x >> 3) & 7;

    const int nt2 = w >> 1;          // P2 roles (R17)
    const int bt2 = w & 1;
    const bool two = (w < 2);        // note: for w<2, bt2 == w

    const f32x16 fzero = {};

#define MFMA32(a, b, c) __builtin_amdgcn_mfma_f32_32x32x16_bf16(a, b, c, 0, 0, 0)
#define SEP asm volatile("" ::: "memory")

// ---------- phase 0: h0 = tanh(x @ W0' + TC*b0), half gb; single acc temp ----
#define PH0(gb) do {                                                          \
    _Pragma("unroll")                                                         \
    for (int bt = 0; bt < 2; ++bt) {                                          \
        const float* src = points + (row0 + (gb) + bt * 32 + ln) * 16 + hi * 8; \
        float4 p0 = ((const float4*)src)[0], p1 = ((const float4*)src)[1];    \
        bf16x8 bx;                                                            \
        bx[0]=(__bf16)p0.x; bx[1]=(__bf16)p0.y; bx[2]=(__bf16)p0.z; bx[3]=(__bf16)p0.w; \
        bx[4]=(__bf16)p1.x; bx[5]=(__bf16)p1.y; bx[6]=(__bf16)p1.z; bx[7]=(__bf16)p1.w; \
        _Pragma("unroll")                                                     \
        for (int t = 0; t < 2; ++t) {                                         \
            const int ntg = w * 2 + t;                                        \
            bf16x8 wf = *(const bf16x8*)(w0f + ntg * 512 + lofs);             \
            f32x16 ac = {};                                                   \
            ac = MFMA32(wf, bx, ac);                                          \
            _Pragma("unroll")                                                 \
            for (int rg = 0; rg < 4; ++rg) {                                  \
                const int n0 = ntg * 32 + 8 * rg + 4 * hi;                    \
                float4 bias = *(const float4*)(b0 + n0);                      \
                bf16x4 v;                                                     \
                v[0]=(__bf16)fast_tanh_pre(fmaf(TC,bias.x,ac[4*rg+0]));       \
                v[1]=(__bf16)fast_tanh_pre(fmaf(TC,bias.y,ac[4*rg+1]));       \
                v[2]=(__bf16)fast_tanh_pre(fmaf(TC,bias.z,ac[4*rg+2]));       \
                v[3]=(__bf16)fast_tanh_pre(fmaf(TC,bias.w,ac[4*rg+3]));       \
                *(bf16x4*)(h + ((gb) + bt * 32 + ln) * HSTR + n0) = v;        \
            }                                                                 \
        }                                                                     \
    }                                                                         \
} while (0)

// ---------- P1 MFMA (verbatim R17 body, per half gb): acc 64 AGPR ----------
#define P1M(gb, A00, A01, A10, A11) do {                                      \
    A00 = fzero; A01 = fzero; A10 = fzero; A11 = fzero;                       \
    const __bf16* arow0 = h + ((gb) + ln) * HSTR + hi * 8;                    \
    const __bf16* arow1 = h + ((gb) + 32 + ln) * HSTR + hi * 8;               \
    const __bf16* wb0 = w1f + (w * 2 + 0) * 16384 + lofs;                     \
    const __bf16* wb1 = w1f + (w * 2 + 1) * 16384 + lofs;                     \
    for (int ks2 = 0; ks2 < 16; ++ks2) {                                      \
        const int ks = (ks2 + ofs16) & 15;                                    \
        bf16x8 aa00, aa01, aa10, aa11, bb00, bb01, bb10, bb11;                \
        {   const int kk = ks * 2;                                            \
            aa00 = *(const bf16x8*)(arow0 + kk * 16);                         \
            aa01 = *(const bf16x8*)(arow1 + kk * 16);                         \
            bb00 = *(const bf16x8*)(wb0 + kk * 512);                          \
            bb01 = *(const bf16x8*)(wb1 + kk * 512); }                        \
        {   const int kk = ks * 2 + 1;                                        \
            aa10 = *(const bf16x8*)(arow0 + kk * 16);                         \
            aa11 = *(const bf16x8*)(arow1 + kk * 16);                         \
            bb10 = *(const bf16x8*)(wb0 + kk * 512);                          \
            bb11 = *(const bf16x8*)(wb1 + kk * 512); }                        \
        A00 = MFMA32(bb00, aa00, A00);  A01 = MFMA32(bb01, aa00, A01);        \
        A10 = MFMA32(bb00, aa01, A10);  A11 = MFMA32(bb01, aa01, A11);        \
        A00 = MFMA32(bb10, aa10, A00);  A01 = MFMA32(bb11, aa10, A01);        \
        A10 = MFMA32(bb10, aa11, A10);  A11 = MFMA32(bb11, aa11, A11);        \
    }                                                                         \
} while (0)

// ---------- P1 epilogue: h1 = tanh(A + TC*b1), half gb ----------
#define P1E(gb, A00, A01, A10, A11) do {                                      \
    _Pragma("unroll")                                                         \
    for (int rg = 0; rg < 4; ++rg) {                                          \
        const int n0a = (w * 2 + 0) * 32 + 8 * rg + 4 * hi;                   \
        const int n0b = (w * 2 + 1) * 32 + 8 * rg + 4 * hi;                   \
        float4 ba = *(const float4*)(b1 + n0a);                               \
        float4 bb = *(const float4*)(b1 + n0b);                               \
        bf16x4 v;                                                             \
        v[0]=(__bf16)fast_tanh_pre(fmaf(TC,ba.x,A00[4*rg+0]));                \
        v[1]=(__bf16)fast_tanh_pre(fmaf(TC,ba.y,A00[4*rg+1]));                \
        v[2]=(__bf16)fast_tanh_pre(fmaf(TC,ba.z,A00[4*rg+2]));                \
        v[3]=(__bf16)fast_tanh_pre(fmaf(TC,ba.w,A00[4*rg+3]));                \
        *(bf16x4*)(h + ((gb) + ln) * HSTR + n0a) = v;                         \
        v[0]=(__bf16)fast_tanh_pre(fmaf(TC,bb.x,A01[4*rg+0]));                \
        v[1]=(__bf16)fast_tanh_pre(fmaf(TC,bb.y,A01[4*rg+1]));                \
        v[2]=(__bf16)fast_tanh_pre(fmaf(TC,bb.z,A01[4*rg+2]));                \
        v[3]=(__bf16)fast_tanh_pre(fmaf(TC,bb.w,A01[4*rg+3]));                \
        *(bf16x4*)(h + ((gb) + ln) * HSTR + n0b) = v;                         \
        v[0]=(__bf16)fast_tanh_pre(fmaf(TC,ba.x,A10[4*rg+0]));                \
        v[1]=(__bf16)fast_tanh_pre(fmaf(TC,ba.y,A10[4*rg+1]));                \
        v[2]=(__bf16)fast_tanh_pre(fmaf(TC,ba.z,A10[4*rg+2]));                \
        v[3]=(__bf16)fast_tanh_pre(fmaf(TC,ba.w,A10[4*rg+3]));                \
        *(bf16x4*)(h + ((gb) + 32 + ln) * HSTR + n0a) = v;                    \
        v[0]=(__bf16)fast_tanh_pre(fmaf(TC,bb.x,A11[4*rg+0]));                \
        v[1]=(__bf16)fast_tanh_pre(fmaf(TC,bb.y,A11[4*rg+1]));                \
        v[2]=(__bf16)fast_tanh_pre(fmaf(TC,bb.z,A11[4*rg+2]));                \
        v[3]=(__bf16)fast_tanh_pre(fmaf(TC,bb.w,A11[4*rg+3]));                \
        *(bf16x4*)(h + ((gb) + 32 + ln) * HSTR + n0b) = v;                    \
    }                                                                         \
} while (0)

// ---------- P2 MFMA, SLIM (2-deep, E shares A rows since bt2==w for w<2) ----
#define P2M(gb, CA, CE) do {                                                  \
    CA = fzero; CE = fzero;                                                   \
    const __bf16* arowA = h + ((gb) + bt2 * 32 + ln) * HSTR + hi * 8;         \
    const __bf16* wbA = w2f + nt2 * 16384 + lofs;                             \
    const __bf16* wbE = w2f + 4 * 16384 + lofs;                               \
    for (int ks2 = 0; ks2 < 8; ++ks2) {                                       \
        const int ks = (ks2 + ofs8) & 7;                                      \
        _Pragma("unroll")                                                     \
        for (int u = 0; u < 2; ++u) {                                         \
            const int kk = ks * 4 + u * 2;                                    \
            bf16x8 a0 = *(const bf16x8*)(arowA + kk * 16);                    \
            bf16x8 a1 = *(const bf16x8*)(arowA + (kk + 1) * 16);              \
            bf16x8 w0v = *(const bf16x8*)(wbA + kk * 512);                    \
            bf16x8 w1v = *(const bf16x8*)(wbA + (kk + 1) * 512);              \
            CA = MFMA32(w0v, a0, CA);                                         \
            CA = MFMA32(w1v, a1, CA);                                         \
            if (two) {                                                        \
                bf16x8 e0 = *(const bf16x8*)(wbE + kk * 512);                 \
                bf16x8 e1 = *(const bf16x8*)(wbE + (kk + 1) * 512);           \
                CE = MFMA32(e0, a0, CE);                                      \
                CE = MFMA32(e1, a1, CE);                                      \
            }                                                                 \
        }                                                                     \
    }                                                                         \
} while (0)

// ---------- P2 epilogue: net = C + b2 (f32), half gb ----------
#define P2E(gb, CA, CE) do {                                                  \
    _Pragma("unroll")                                                         \
    for (int rg = 0; rg < 4; ++rg) {                                          \
        const int n0 = nt2 * 32 + 8 * rg + 4 * hi;                            \
        float4 bias = *(const float4*)(b2 + n0);                              \
        float4 v;                                                             \
        v.x = CA[4*rg+0] + bias.x; v.y = CA[4*rg+1] + bias.y;                 \
        v.z = CA[4*rg+2] + bias.z; v.w = CA[4*rg+3] + bias.w;                 \
        *(float4*)(net + ((gb) + bt2 * 32 + ln) * NSTR + n0) = v;             \
    }                                                                         \
    if (two) {                                                                \
        const int n0 = 128 + 4 * hi;                                          \
        float4 bias = *(const float4*)(b2 + n0);                              \
        float4 v;                                                             \
        v.x = CE[0] + bias.x; v.y = CE[1] + bias.y;                           \
        v.z = CE[2] + bias.z; v.w = CE[3] + bias.w;                           \
        *(float4*)(net + ((gb) + bt2 * 32 + ln) * NSTR + n0) = v;             \
    }                                                                         \
} while (0)

// ---------- P3: vals, half gb (8 thr/row x 64 rows) ----------
#define PH3(gb) do {                                                          \
    const int rl = tid >> 3;                                                  \
    const int jg = tid & 7;                                                   \
    const float* xp = points + (row0 + (gb) + rl) * 16;                       \
    float xv[16];                                                             \
    _Pragma("unroll")                                                         \
    for (int i = 0; i < 4; ++i) {                                             \
        float4 v = ((const float4*)xp)[i];                                    \
        xv[i*4+0] = v.x; xv[i*4+1] = v.y; xv[i*4+2] = v.z; xv[i*4+3] = v.w;   \
    }                                                                         \
    float sumsq = 0.f;                                                        \
    _Pragma("unroll")                                                         \
    for (int i = 0; i < 16; ++i) sumsq += xv[i] * xv[i];                      \
    float p = 0.f;                                                            \
    _Pragma("unroll")                                                         \
    for (int jj = 0; jj < 2; ++jj) {                                          \
        const int j = jg + jj * 8;                                            \
        float y = 0.f;                                                        \
        _Pragma("unroll")                                                     \
        for (int i = 0; i < 16; ++i) {                                        \
            float mv = net[((gb) + rl) * NSTR + ((i * (i + 1)) >> 1) + j];    \
            y += (i >= j) ? mv * xv[i] : 0.f;                                 \
        }                                                                     \
        p += y * y;                                                           \
    }                                                                         \
    p += __shfl_xor(p, 1);                                                    \
    p += __shfl_xor(p, 2);                                                    \
    p += __shfl_xor(p, 4);                                                    \
    if (jg == 0) out[row0 + (gb) + rl] = p + 1e-6f * sumsq;                   \
} while (0)

    // ---------- anti-phased schedule over halves A(gb=0), B(gb=64) ----------
    // LDS liveness per segment re-verified: net(A)=bytes 0..35839 overlays
    // h rows 0..34 (group A, dead after S3); net(B)=35840..71679 overlays
    // h rows 35..68 (A-dead after S3, B rows 64-68 dead after S4).
    f32x16 a1A00, a1A01, a1A10, a1A11;
    f32x16 a1B00, a1B01, a1B10, a1B11;
    f32x16 c2aA, c2eA, c2aB, c2eB;

    PH0(0);                                              // S0
    __syncthreads();
    if (w < 4) { P1M(0, a1A00, a1A01, a1A10, a1A11); SEP; PH0(64); }
    else       { PH0(64); SEP; P1M(0, a1A00, a1A01, a1A10, a1A11); }
    __syncthreads();                                     // S1
    if (w < 4) { P1M(64, a1B00, a1B01, a1B10, a1B11); SEP; P1E(0, a1A00, a1A01, a1A10, a1A11); }
    else       { P1E(0, a1A00, a1A01, a1A10, a1A11); SEP; P1M(64, a1B00, a1B01, a1B10, a1B11); }
    __syncthreads();                                     // S2
    if (w < 4) { P2M(0, c2aA, c2eA); SEP; P1E(64, a1B00, a1B01, a1B10, a1B11); }
    else       { P1E(64, a1B00, a1B01, a1B10, a1B11); SEP; P2M(0, c2aA, c2eA); }
    __syncthreads();                                     // S3
    if (w < 4) { P2M(64, c2aB, c2eB); SEP; P2E(0, c2aA, c2eA); }
    else       { P2E(0, c2aA, c2eA); SEP; P2M(64, c2aB, c2eB); }
    __syncthreads();                                     // S4
    P2E(64, c2aB, c2eB); SEP; PH3(0);                    // S5 (disjoint rows)
    __syncthreads();
    PH3(64);                                             // S6
}

extern "C" void kernel_launch(void* const* d_in, const int* in_sizes, int n_in,
                              void* d_out, int out_size, void* d_ws, size_t ws_size,
                              hipStream_t stream) {
    const float* points = (const float*)d_in[0];
    const float* W0 = (const float*)d_in[1];
    const float* b0 = (const float*)d_in[2];
    const float* W1 = (const float*)d_in[3];
    const float* b1 = (const float*)d_in[4];
    const float* W2 = (const float*)d_in[5];
    const float* b2 = (const float*)d_in[6];
    __bf16* ws = (__bf16*)d_ws;
    float* out = (float*)d_out;

    prep_weights<<<86, 512, 0, stream>>>(W0, W1, W2, ws);

    const int B = in_sizes[0] / 16;   // 131072
    fused_mlp_quad<<<B / 128, 512, 0, stream>>>(points, b0, b1, b2, ws, out);
}

// Round 7
// 196.784 us; speedup vs baseline: 1.0913x; 1.0913x over previous
//
#include <hip/hip_runtime.h>

typedef __bf16 bf16x4 __attribute__((ext_vector_type(4)));
typedef __bf16 bf16x8 __attribute__((ext_vector_type(8)));
typedef float f32x16 __attribute__((ext_vector_type(16)));

#define TC 2.885390081777926f   // 2/ln2, folded into W0/W1 at prep

// ---- workspace layout (bf16 element offsets), FRAGMENT-ORDERED weights ----
// 1 KB record per (nt,kk): elem (lane,j) at rec*512 + lane*8 + j
//   n = nt*32 + (lane&31), k = kk*16 + (lane>>5)*8 + j
#define W0F_OFF 0                 // 16 recs
#define W1F_OFF 8192              // 512 recs
#define W2F_OFF (8192 + 262144)   // 160 recs (n>=136 zero)

// One wave per 1KB record: coalesced row reads, coalesced dwordx4 stores.
// W0/W1 pre-scaled by TC (tanh exp2 scale) -> saves 1 VALU/tanh in the kernel.
__global__ void prep_weights(const float* __restrict__ W0,
                             const float* __restrict__ W1,
                             const float* __restrict__ W2,
                             __bf16* __restrict__ ws) {
    const int wave = blockIdx.x * 8 + (threadIdx.x >> 6);   // 0..687
    const int l   = threadIdx.x & 63;
    const int col = l & 31, kh = l >> 5;
    const float* src; int nt, kk, S, nlim; float scl;
    if (wave < 16)       { src = W0; nt = wave; kk = 0;      S = 512; nlim = 512; scl = TC; }
    else if (wave < 528) { int r = wave - 16;  src = W1; nt = r >> 5; kk = r & 31; S = 512; nlim = 512; scl = TC; }
    else                 { int r = wave - 528; src = W2; nt = r >> 5; kk = r & 31; S = 136; nlim = 136; scl = 1.0f; }
    const int n  = nt * 32 + col;
    const int k0 = kk * 16 + kh * 8;
    bf16x8 v;
#pragma unroll
    for (int j = 0; j < 8; ++j)
        v[j] = (n < nlim) ? (__bf16)(src[(k0 + j) * S + n] * scl) : (__bf16)0.0f;
    *(bf16x8*)(ws + wave * 512 + l * 8) = v;
}

// input y is pre-scaled by TC: tanh(x) = 1 - 2/(exp2(TC*x)+1)
__device__ __forceinline__ float fast_tanh_pre(float y) {
#if __has_builtin(__builtin_amdgcn_exp2f)
    float e = __builtin_amdgcn_exp2f(y);
#else
    float e = exp2f(y);
#endif
    return 1.0f - 2.0f * __builtin_amdgcn_rcpf(e + 1.0f);
}

// h LDS: [64][520] bf16 (rows 1040 B, 16B-aligned), ds_read_b128.
#define HSTR 520
// net LDS: [64][140] f32 overlay (float4-aligned rows).
#define NSTR 140

// R24 = R23 resubmitted (R6 was an infra failure: "container failed twice",
// no compile/correctness signal; nothing in R23 can hang -- bounded scalar
// s_sleep chain only). R17 EXACT core (136.6us proven: BM=64, 8 waves,
// 2nt x 2bt, acc=64 AGPR, VGPR=64 -> 2 blocks/CU, 4 waves/SIMD) + coalesced
// prep (R19) + TC-folded weights (R21/R22 correctness-proven) + GENERATION
// STAGGER probe: pipe-busy decomposition (MFMA 41 + VALU 48 + LDS 30 ~= 136us)
// says the kernel runs at the zero-overlap serial sum of its pipes, invariant
// to occupancy/AI/pipelining; remaining theory is convoy lockstep (all
// resident blocks phase-synchronized forever, m114 overlap never triggers).
// Stagger first-generation blocks 0-14us via hashed s_sleep chain (zero
// register/pipe cost); stagger self-perpetuates across generations.
// Tripwires: VGPR=64, WRITE_SIZE~512KB. Prediction: success 120-128us /
// null 137-141us.
__global__ __launch_bounds__(512, 2)
void fused_mlp_quad(const float* __restrict__ points,
                    const float* __restrict__ b0,
                    const float* __restrict__ b1,
                    const float* __restrict__ b2,
                    const __bf16* __restrict__ ws,
                    float* __restrict__ out) {
    __shared__ __align__(16) unsigned char lds_raw[66560];
    __bf16* h  = (__bf16*)lds_raw;   // [64][HSTR] bf16 (h0, then h1 in place)
    float* net = (float*)lds_raw;    // [64][NSTR] f32 overlay after phase 2

    // ---- generation stagger (convoy de-phasing probe), branch-chain form ----
    {
        const unsigned d = (blockIdx.x < 512)
                         ? ((blockIdx.x * 2654435761u) >> 29) : 0u;  // 0..7
        if (d > 0) __builtin_amdgcn_s_sleep(64);   // ~4096 cyc each
        if (d > 1) __builtin_amdgcn_s_sleep(64);
        if (d > 2) __builtin_amdgcn_s_sleep(64);
        if (d > 3) __builtin_amdgcn_s_sleep(64);
        if (d > 4) __builtin_amdgcn_s_sleep(64);
        if (d > 5) __builtin_amdgcn_s_sleep(64);
        if (d > 6) __builtin_amdgcn_s_sleep(64);
    }

    const __bf16* w0f = ws + W0F_OFF;
    const __bf16* w1f = ws + W1F_OFF;
    const __bf16* w2f = ws + W2F_OFF;

    const int tid = threadIdx.x;
    const int w   = tid >> 6;     // wave 0..7
    const int l   = tid & 63;
    const int ln  = l & 31;       // batch row within tile / 32x32 lane index
    const int hi  = l >> 5;       // k-half
    const int row0 = blockIdx.x * 64;

    const int lofs = l * 8;       // lane offset within a 1KB fragment record
    const int ofs16 = (blockIdx.x >> 3) & 15;   // K-rotation (16-way per XCD)
    const int ofs8  = (blockIdx.x >> 3) & 7;

    // ---------- phase 0: h0 = tanh(x @ W0' + TC*b0), K=16 = one MFMA step ----------
    {
        bf16x8 bx[2];
#pragma unroll
        for (int bt = 0; bt < 2; ++bt) {
            const float* src = points + (row0 + bt * 32 + ln) * 16 + hi * 8;
            float4 p0 = ((const float4*)src)[0];
            float4 p1 = ((const float4*)src)[1];
            bf16x8 v;
            v[0] = (__bf16)p0.x; v[1] = (__bf16)p0.y; v[2] = (__bf16)p0.z; v[3] = (__bf16)p0.w;
            v[4] = (__bf16)p1.x; v[5] = (__bf16)p1.y; v[6] = (__bf16)p1.z; v[7] = (__bf16)p1.w;
            bx[bt] = v;
        }
#pragma unroll
        for (int t = 0; t < 2; ++t) {
            const int ntg = w * 2 + t;
            bf16x8 wf = *(const bf16x8*)(w0f + ntg * 512 + lofs);
#pragma unroll
            for (int bt = 0; bt < 2; ++bt) {
                f32x16 acc = {};
                acc = __builtin_amdgcn_mfma_f32_32x32x16_bf16(wf, bx[bt], acc, 0, 0, 0);
#pragma unroll
                for (int rg = 0; rg < 4; ++rg) {
                    const int n0 = ntg * 32 + 8 * rg + 4 * hi;
                    float4 bias = *(const float4*)(b0 + n0);
                    bf16x4 v;
                    v[0] = (__bf16)fast_tanh_pre(fmaf(TC, bias.x, acc[4 * rg + 0]));
                    v[1] = (__bf16)fast_tanh_pre(fmaf(TC, bias.y, acc[4 * rg + 1]));
                    v[2] = (__bf16)fast_tanh_pre(fmaf(TC, bias.z, acc[4 * rg + 2]));
                    v[3] = (__bf16)fast_tanh_pre(fmaf(TC, bias.w, acc[4 * rg + 3]));
                    *(bf16x4*)(h + (bt * 32 + ln) * HSTR + n0) = v;
                }
            }
        }
    }
    __syncthreads();

    // ---------- phase 1: h1 = tanh(h0 @ W1' + TC*b1) ----------
    // wave: 2 nt x 2 bt; acc = 64 AGPR. Batch-2 super-iters, ROTATED start.
    f32x16 acc1[2][2] = {};   // [bt][t]
    {
        const __bf16* arow0 = h + ln * HSTR + hi * 8;          // bt=0
        const __bf16* arow1 = h + (32 + ln) * HSTR + hi * 8;   // bt=1
        const __bf16* wb0 = w1f + (w * 2 + 0) * 16384 + lofs;
        const __bf16* wb1 = w1f + (w * 2 + 1) * 16384 + lofs;
        for (int ks2 = 0; ks2 < 16; ++ks2) {
            const int ks = (ks2 + ofs16) & 15;   // block-dependent rotation
            bf16x8 aa[2][2], bb[2][2];
#pragma unroll
            for (int u = 0; u < 2; ++u) {
                const int kk = ks * 2 + u;
                const int vo = kk * 512;
                aa[u][0] = *(const bf16x8*)(arow0 + kk * 16);
                aa[u][1] = *(const bf16x8*)(arow1 + kk * 16);
                bb[u][0] = *(const bf16x8*)(wb0 + vo);
                bb[u][1] = *(const bf16x8*)(wb1 + vo);
            }
#pragma unroll
            for (int u = 0; u < 2; ++u) {
#pragma unroll
                for (int t = 0; t < 2; ++t) {
                    acc1[0][t] = __builtin_amdgcn_mfma_f32_32x32x16_bf16(bb[u][t], aa[u][0], acc1[0][t], 0, 0, 0);
                    acc1[1][t] = __builtin_amdgcn_mfma_f32_32x32x16_bf16(bb[u][t], aa[u][1], acc1[1][t], 0, 0, 0);
                }
            }
        }
    }
    __syncthreads();   // all h0 reads done; overwrite in place
#pragma unroll
    for (int t = 0; t < 2; ++t) {
#pragma unroll
        for (int bt = 0; bt < 2; ++bt) {
#pragma unroll
            for (int rg = 0; rg < 4; ++rg) {
                const int n0 = (w * 2 + t) * 32 + 8 * rg + 4 * hi;
                float4 bias = *(const float4*)(b1 + n0);
                bf16x4 v;
                v[0] = (__bf16)fast_tanh_pre(fmaf(TC, bias.x, acc1[bt][t][4 * rg + 0]));
                v[1] = (__bf16)fast_tanh_pre(fmaf(TC, bias.y, acc1[bt][t][4 * rg + 1]));
                v[2] = (__bf16)fast_tanh_pre(fmaf(TC, bias.z, acc1[bt][t][4 * rg + 2]));
                v[3] = (__bf16)fast_tanh_pre(fmaf(TC, bias.w, acc1[bt][t][4 * rg + 3]));
                *(bf16x4*)(h + (bt * 32 + ln) * HSTR + n0) = v;
            }
        }
    }
    __syncthreads();

    // ---------- phase 2: net = h1 @ W2 + b2 (N pad 160: 5 nt x 2 bt = 10 tiles) ----
    // wave w: tile (nt = w>>1, bt = w&1); waves 0,1 also tile (nt=4, bt=w).
    f32x16 acc2a = {}, acc2e = {};
    const int nt2 = w >> 1;
    const int bt2 = w & 1;
    const bool two = (w < 2);
    {
        const __bf16* arowA = h + (bt2 * 32 + ln) * HSTR + hi * 8;
        const __bf16* arowE = h + ((w & 1) * 32 + ln) * HSTR + hi * 8;  // bt=w for w<2
        const __bf16* wbA = w2f + nt2 * 16384 + lofs;
        const __bf16* wbE = w2f + 4 * 16384 + lofs;
        for (int ks2 = 0; ks2 < 8; ++ks2) {
            const int ks = (ks2 + ofs8) & 7;     // block-dependent rotation
            bf16x8 aaA[2], wA[2], aaE[2], wE[2];
#pragma unroll
            for (int u = 0; u < 2; ++u) {
                const int kk = ks * 4 + u * 2;   // two kk per u-step (batch-2 of pairs)
                const int vo = kk * 512;
                aaA[u] = *(const bf16x8*)(arowA + kk * 16);
                wA[u]  = *(const bf16x8*)(wbA + vo);
                if (two) {
                    aaE[u] = *(const bf16x8*)(arowE + kk * 16);
                    wE[u]  = *(const bf16x8*)(wbE + vo);
                }
            }
            bf16x8 aaA2[2], wA2[2], aaE2[2], wE2[2];
#pragma unroll
            for (int u = 0; u < 2; ++u) {
                const int kk = ks * 4 + u * 2 + 1;
                const int vo = kk * 512;
                aaA2[u] = *(const bf16x8*)(arowA + kk * 16);
                wA2[u]  = *(const bf16x8*)(wbA + vo);
                if (two) {
                    aaE2[u] = *(const bf16x8*)(arowE + kk * 16);
                    wE2[u]  = *(const bf16x8*)(wbE + vo);
                }
            }
#pragma unroll
            for (int u = 0; u < 2; ++u) {
                acc2a = __builtin_amdgcn_mfma_f32_32x32x16_bf16(wA[u], aaA[u], acc2a, 0, 0, 0);
                acc2a = __builtin_amdgcn_mfma_f32_32x32x16_bf16(wA2[u], aaA2[u], acc2a, 0, 0, 0);
                if (two) {
                    acc2e = __builtin_amdgcn_mfma_f32_32x32x16_bf16(wE[u], aaE[u], acc2e, 0, 0, 0);
                    acc2e = __builtin_amdgcn_mfma_f32_32x32x16_bf16(wE2[u], aaE2[u], acc2e, 0, 0, 0);
                }
            }
        }
    }
    __syncthreads();   // all h1 reads done; overwrite with net (fp32)
    {
#pragma unroll
        for (int rg = 0; rg < 4; ++rg) {
            const int n0 = nt2 * 32 + 8 * rg + 4 * hi;   // <= 127 < 136
            float4 bias = *(const float4*)(b2 + n0);
            float4 v;
            v.x = acc2a[4 * rg + 0] + bias.x;
            v.y = acc2a[4 * rg + 1] + bias.y;
            v.z = acc2a[4 * rg + 2] + bias.z;
            v.w = acc2a[4 * rg + 3] + bias.w;
            *(float4*)(net + (bt2 * 32 + ln) * NSTR + n0) = v;
        }
        if (two) {
            // extra tile nt=4 (n 128..135): only rg==0 in range (n0=128/132)
            const int n0 = 128 + 4 * hi;
            float4 bias = *(const float4*)(b2 + n0);
            float4 v;
            v.x = acc2e[0] + bias.x;
            v.y = acc2e[1] + bias.y;
            v.z = acc2e[2] + bias.z;
            v.w = acc2e[3] + bias.w;
            *(float4*)(net + ((w & 1) * 32 + ln) * NSTR + n0) = v;
        }
    }
    __syncthreads();

    // ---------- phase 3: vals = ||M^T x||^2 + eps*||x||^2 ----------
    // 8 threads per row x 64 rows = 512 threads, single pass
    {
        const int r  = tid >> 3;
        const int jg = tid & 7;
        const float* xp = points + (row0 + r) * 16;
        float xv[16];
#pragma unroll
        for (int i = 0; i < 4; ++i) {
            float4 v = ((const float4*)xp)[i];
            xv[i * 4 + 0] = v.x; xv[i * 4 + 1] = v.y;
            xv[i * 4 + 2] = v.z; xv[i * 4 + 3] = v.w;
        }
        float sumsq = 0.f;
#pragma unroll
        for (int i = 0; i < 16; ++i) sumsq += xv[i] * xv[i];
        float p = 0.f;
#pragma unroll
        for (int jj = 0; jj < 2; ++jj) {
            const int j = jg + jj * 8;
            float y = 0.f;
#pragma unroll
            for (int i = 0; i < 16; ++i) {
                float mv = net[r * NSTR + ((i * (i + 1)) >> 1) + j];
                y += (i >= j) ? mv * xv[i] : 0.f;
            }
            p += y * y;
        }
        p += __shfl_xor(p, 1);
        p += __shfl_xor(p, 2);
        p += __shfl_xor(p, 4);
        if (jg == 0) out[row0 + r] = p + 1e-6f * sumsq;
    }
}

extern "C" void kernel_launch(void* const* d_in, const int* in_sizes, int n_in,
                              void* d_out, int out_size, void* d_ws, size_t ws_size,
                              hipStream_t stream) {
    const float* points = (const float*)d_in[0];
    const float* W0 = (const float*)d_in[1];
    const float* b0 = (const float*)d_in[2];
    const float* W1 = (const float*)d_in[3];
    const float* b1 = (const float*)d_in[4];
    const float* W2 = (const float*)d_in[5];
    const float* b2 = (const float*)d_in[6];
    __bf16* ws = (__bf16*)d_ws;
    float* out = (float*)d_out;

    prep_weights<<<86, 512, 0, stream>>>(W0, W1, W2, ws);

    const int B = in_sizes[0] / 16;   // 131072
    fused_mlp_quad<<<B / 64, 512, 0, stream>>>(points, b0, b1, b2, ws, out);
}

// Round 8
// 195.555 us; speedup vs baseline: 1.0981x; 1.0063x over previous
//
#include <hip/hip_runtime.h>

typedef __bf16 bf16x4 __attribute__((ext_vector_type(4)));
typedef __bf16 bf16x8 __attribute__((ext_vector_type(8)));
typedef float f32x16 __attribute__((ext_vector_type(16)));

#define TC 2.885390081777926f   // 2/ln2, folded into W0/W1 at prep

// ---- workspace layout (bf16 element offsets), FRAGMENT-ORDERED weights ----
// 1 KB record per (nt,kk): elem (lane,j) at rec*512 + lane*8 + j
//   n = nt*32 + (lane&31), k = kk*16 + (lane>>5)*8 + j
#define W0F_OFF 0                 // 16 recs
#define W1F_OFF 8192              // 512 recs
#define W2F_OFF (8192 + 262144)   // 160 recs (n>=136 zero)

// One wave per 1KB record: coalesced row reads, coalesced dwordx4 stores.
// W0/W1 pre-scaled by TC (tanh exp2 scale) -> saves 1 VALU/tanh in the kernel.
__global__ void prep_weights(const float* __restrict__ W0,
                             const float* __restrict__ W1,
                             const float* __restrict__ W2,
                             __bf16* __restrict__ ws) {
    const int wave = blockIdx.x * 8 + (threadIdx.x >> 6);   // 0..687
    const int l   = threadIdx.x & 63;
    const int col = l & 31, kh = l >> 5;
    const float* src; int nt, kk, S, nlim; float scl;
    if (wave < 16)       { src = W0; nt = wave; kk = 0;      S = 512; nlim = 512; scl = TC; }
    else if (wave < 528) { int r = wave - 16;  src = W1; nt = r >> 5; kk = r & 31; S = 512; nlim = 512; scl = TC; }
    else                 { int r = wave - 528; src = W2; nt = r >> 5; kk = r & 31; S = 136; nlim = 136; scl = 1.0f; }
    const int n  = nt * 32 + col;
    const int k0 = kk * 16 + kh * 8;
    bf16x8 v;
#pragma unroll
    for (int j = 0; j < 8; ++j)
        v[j] = (n < nlim) ? (__bf16)(src[(k0 + j) * S + n] * scl) : (__bf16)0.0f;
    *(bf16x8*)(ws + wave * 512 + l * 8) = v;
}

// input y is pre-scaled by TC: tanh(x) = 1 - 2/(exp2(TC*x)+1)
__device__ __forceinline__ float fast_tanh_pre(float y) {
#if __has_builtin(__builtin_amdgcn_exp2f)
    float e = __builtin_amdgcn_exp2f(y);
#else
    float e = exp2f(y);
#endif
    return 1.0f - 2.0f * __builtin_amdgcn_rcpf(e + 1.0f);
}

// h LDS: [64][520] bf16 (rows 1040 B, 16B-aligned) + BANK SWIZZLE (below).
#define HSTR 520
// net LDS: [64][140] f32 overlay (float4-aligned rows), NOT swizzled.
#define NSTR 140

// R25 = R17 core (136.6us proven: BM=64, 8 waves, 2nt x 2bt, acc=64 AGPR,
// VGPR~56 -> 2 blocks/CU, 4 waves/SIMD) + coalesced prep + TC-folded weights
// + H BANK-CONFLICT SWIZZLE. Stagger (R24) removed: null (141 ~ 136+tail).
// Counter evidence: SQ_LDS_BANK_CONFLICT = 2.62M (constant all rounds)
// ~= 4.3us/CU. Cause: row stride 1040 B == 4 banks (mod 32), so ds_read_b128
// of rows bt*32+ln puts lanes {ln, ln+8, ln+16, ln+24} on the same 4-bank
// group -> 4-way conflict on every P1/P2 A-read and epilogue write.
// Fix (T2-style): XOR element-offset bits 4-5 with q=(row>>3)&3. All h
// accesses are 16B-block aligned, so this folds to: reads use kk^q, writes
// XOR n0 with q<<4. Weights keep logical kk (MFMA pairing untouched).
// Bijective per row; 8B/16B accesses never straddle flipped bits; net/P3
// overlay unaffected (consumed after barriers, linear indexing).
// Predictions: conflicts < 1M; dur 130-134 if on critical path (135-140 if
// masked); VGPR ~56-64; WRITE_SIZE ~512KB.
__global__ __launch_bounds__(512, 2)
void fused_mlp_quad(const float* __restrict__ points,
                    const float* __restrict__ b0,
                    const float* __restrict__ b1,
                    const float* __restrict__ b2,
                    const __bf16* __restrict__ ws,
                    float* __restrict__ out) {
    __shared__ __align__(16) unsigned char lds_raw[66560];
    __bf16* h  = (__bf16*)lds_raw;   // [64][HSTR] bf16 (h0, then h1 in place)
    float* net = (float*)lds_raw;    // [64][NSTR] f32 overlay after phase 2

    const __bf16* w0f = ws + W0F_OFF;
    const __bf16* w1f = ws + W1F_OFF;
    const __bf16* w2f = ws + W2F_OFF;

    const int tid = threadIdx.x;
    const int w   = tid >> 6;     // wave 0..7
    const int l   = tid & 63;
    const int ln  = l & 31;       // batch row within tile / 32x32 lane index
    const int hi  = l >> 5;       // k-half
    const int row0 = blockIdx.x * 64;

    const int lofs = l * 8;       // lane offset within a 1KB fragment record
    const int ofs16 = (blockIdx.x >> 3) & 15;   // K-rotation (16-way per XCD)
    const int ofs8  = (blockIdx.x >> 3) & 7;

    // ---- h bank swizzle: q = (row>>3)&3; rows are bt*32+ln -> q = (ln>>3)&3
    const int kq   = (ln >> 3) & 3;    // XOR into kk for 16B-block reads
    const int hswz = kq << 4;          // XOR into n0 (elements) for writes

    // ---------- phase 0: h0 = tanh(x @ W0' + TC*b0), K=16 = one MFMA step ----------
    {
        bf16x8 bx[2];
#pragma unroll
        for (int bt = 0; bt < 2; ++bt) {
            const float* src = points + (row0 + bt * 32 + ln) * 16 + hi * 8;
            float4 p0 = ((const float4*)src)[0];
            float4 p1 = ((const float4*)src)[1];
            bf16x8 v;
            v[0] = (__bf16)p0.x; v[1] = (__bf16)p0.y; v[2] = (__bf16)p0.z; v[3] = (__bf16)p0.w;
            v[4] = (__bf16)p1.x; v[5] = (__bf16)p1.y; v[6] = (__bf16)p1.z; v[7] = (__bf16)p1.w;
            bx[bt] = v;
        }
#pragma unroll
        for (int t = 0; t < 2; ++t) {
            const int ntg = w * 2 + t;
            bf16x8 wf = *(const bf16x8*)(w0f + ntg * 512 + lofs);
#pragma unroll
            for (int bt = 0; bt < 2; ++bt) {
                f32x16 acc = {};
                acc = __builtin_amdgcn_mfma_f32_32x32x16_bf16(wf, bx[bt], acc, 0, 0, 0);
#pragma unroll
                for (int rg = 0; rg < 4; ++rg) {
                    const int n0 = ntg * 32 + 8 * rg + 4 * hi;
                    float4 bias = *(const float4*)(b0 + n0);
                    bf16x4 v;
                    v[0] = (__bf16)fast_tanh_pre(fmaf(TC, bias.x, acc[4 * rg + 0]));
                    v[1] = (__bf16)fast_tanh_pre(fmaf(TC, bias.y, acc[4 * rg + 1]));
                    v[2] = (__bf16)fast_tanh_pre(fmaf(TC, bias.z, acc[4 * rg + 2]));
                    v[3] = (__bf16)fast_tanh_pre(fmaf(TC, bias.w, acc[4 * rg + 3]));
                    *(bf16x4*)(h + (bt * 32 + ln) * HSTR + (n0 ^ hswz)) = v;
                }
            }
        }
    }
    __syncthreads();

    // ---------- phase 1: h1 = tanh(h0 @ W1' + TC*b1) ----------
    // wave: 2 nt x 2 bt; acc = 64 AGPR. Batch-2 super-iters, ROTATED start.
    f32x16 acc1[2][2] = {};   // [bt][t]
    {
        const __bf16* arow0 = h + ln * HSTR + hi * 8;          // bt=0
        const __bf16* arow1 = h + (32 + ln) * HSTR + hi * 8;   // bt=1
        const __bf16* wb0 = w1f + (w * 2 + 0) * 16384 + lofs;
        const __bf16* wb1 = w1f + (w * 2 + 1) * 16384 + lofs;
        for (int ks2 = 0; ks2 < 16; ++ks2) {
            const int ks = (ks2 + ofs16) & 15;   // block-dependent rotation
            bf16x8 aa[2][2], bb[2][2];
#pragma unroll
            for (int u = 0; u < 2; ++u) {
                const int kk = ks * 2 + u;
                const int kx = kk ^ kq;          // swizzled h read block
                const int vo = kk * 512;         // weights: logical kk
                aa[u][0] = *(const bf16x8*)(arow0 + kx * 16);
                aa[u][1] = *(const bf16x8*)(arow1 + kx * 16);
                bb[u][0] = *(const bf16x8*)(wb0 + vo);
                bb[u][1] = *(const bf16x8*)(wb1 + vo);
            }
#pragma unroll
            for (int u = 0; u < 2; ++u) {
#pragma unroll
                for (int t = 0; t < 2; ++t) {
                    acc1[0][t] = __builtin_amdgcn_mfma_f32_32x32x16_bf16(bb[u][t], aa[u][0], acc1[0][t], 0, 0, 0);
                    acc1[1][t] = __builtin_amdgcn_mfma_f32_32x32x16_bf16(bb[u][t], aa[u][1], acc1[1][t], 0, 0, 0);
                }
            }
        }
    }
    __syncthreads();   // all h0 reads done; overwrite in place
#pragma unroll
    for (int t = 0; t < 2; ++t) {
#pragma unroll
        for (int bt = 0; bt < 2; ++bt) {
#pragma unroll
            for (int rg = 0; rg < 4; ++rg) {
                const int n0 = (w * 2 + t) * 32 + 8 * rg + 4 * hi;
                float4 bias = *(const float4*)(b1 + n0);
                bf16x4 v;
                v[0] = (__bf16)fast_tanh_pre(fmaf(TC, bias.x, acc1[bt][t][4 * rg + 0]));
                v[1] = (__bf16)fast_tanh_pre(fmaf(TC, bias.y, acc1[bt][t][4 * rg + 1]));
                v[2] = (__bf16)fast_tanh_pre(fmaf(TC, bias.z, acc1[bt][t][4 * rg + 2]));
                v[3] = (__bf16)fast_tanh_pre(fmaf(TC, bias.w, acc1[bt][t][4 * rg + 3]));
                *(bf16x4*)(h + (bt * 32 + ln) * HSTR + (n0 ^ hswz)) = v;
            }
        }
    }
    __syncthreads();

    // ---------- phase 2: net = h1 @ W2 + b2 (N pad 160: 5 nt x 2 bt = 10 tiles) ----
    // wave w: tile (nt = w>>1, bt = w&1); waves 0,1 also tile (nt=4, bt=w).
    f32x16 acc2a = {}, acc2e = {};
    const int nt2 = w >> 1;
    const int bt2 = w & 1;
    const bool two = (w < 2);
    {
        const __bf16* arowA = h + (bt2 * 32 + ln) * HSTR + hi * 8;
        const __bf16* arowE = h + ((w & 1) * 32 + ln) * HSTR + hi * 8;  // bt=w for w<2
        const __bf16* wbA = w2f + nt2 * 16384 + lofs;
        const __bf16* wbE = w2f + 4 * 16384 + lofs;
        for (int ks2 = 0; ks2 < 8; ++ks2) {
            const int ks = (ks2 + ofs8) & 7;     // block-dependent rotation
            bf16x8 aaA[2], wA[2], aaE[2], wE[2];
#pragma unroll
            for (int u = 0; u < 2; ++u) {
                const int kk = ks * 4 + u * 2;   // two kk per u-step (batch-2 of pairs)
                const int kx = kk ^ kq;
                const int vo = kk * 512;
                aaA[u] = *(const bf16x8*)(arowA + kx * 16);
                wA[u]  = *(const bf16x8*)(wbA + vo);
                if (two) {
                    aaE[u] = *(const bf16x8*)(arowE + kx * 16);
                    wE[u]  = *(const bf16x8*)(wbE + vo);
                }
            }
            bf16x8 aaA2[2], wA2[2], aaE2[2], wE2[2];
#pragma unroll
            for (int u = 0; u < 2; ++u) {
                const int kk = ks * 4 + u * 2 + 1;
                const int kx = kk ^ kq;
                const int vo = kk * 512;
                aaA2[u] = *(const bf16x8*)(arowA + kx * 16);
                wA2[u]  = *(const bf16x8*)(wbA + vo);
                if (two) {
                    aaE2[u] = *(const bf16x8*)(arowE + kx * 16);
                    wE2[u]  = *(const bf16x8*)(wbE + vo);
                }
            }
#pragma unroll
            for (int u = 0; u < 2; ++u) {
                acc2a = __builtin_amdgcn_mfma_f32_32x32x16_bf16(wA[u], aaA[u], acc2a, 0, 0, 0);
                acc2a = __builtin_amdgcn_mfma_f32_32x32x16_bf16(wA2[u], aaA2[u], acc2a, 0, 0, 0);
                if (two) {
                    acc2e = __builtin_amdgcn_mfma_f32_32x32x16_bf16(wE[u], aaE[u], acc2e, 0, 0, 0);
                    acc2e = __builtin_amdgcn_mfma_f32_32x32x16_bf16(wE2[u], aaE2[u], acc2e, 0, 0, 0);
                }
            }
        }
    }
    __syncthreads();   // all h1 reads done; overwrite with net (fp32, linear)
    {
#pragma unroll
        for (int rg = 0; rg < 4; ++rg) {
            const int n0 = nt2 * 32 + 8 * rg + 4 * hi;   // <= 127 < 136
            float4 bias = *(const float4*)(b2 + n0);
            float4 v;
            v.x = acc2a[4 * rg + 0] + bias.x;
            v.y = acc2a[4 * rg + 1] + bias.y;
            v.z = acc2a[4 * rg + 2] + bias.z;
            v.w = acc2a[4 * rg + 3] + bias.w;
            *(float4*)(net + (bt2 * 32 + ln) * NSTR + n0) = v;
        }
        if (two) {
            // extra tile nt=4 (n 128..135): only rg==0 in range (n0=128/132)
            const int n0 = 128 + 4 * hi;
            float4 bias = *(const float4*)(b2 + n0);
            float4 v;
            v.x = acc2e[0] + bias.x;
            v.y = acc2e[1] + bias.y;
            v.z = acc2e[2] + bias.z;
            v.w = acc2e[3] + bias.w;
            *(float4*)(net + ((w & 1) * 32 + ln) * NSTR + n0) = v;
        }
    }
    __syncthreads();

    // ---------- phase 3: vals = ||M^T x||^2 + eps*||x||^2 ----------
    // 8 threads per row x 64 rows = 512 threads, single pass
    {
        const int r  = tid >> 3;
        const int jg = tid & 7;
        const float* xp = points + (row0 + r) * 16;
        float xv[16];
#pragma unroll
        for (int i = 0; i < 4; ++i) {
            float4 v = ((const float4*)xp)[i];
            xv[i * 4 + 0] = v.x; xv[i * 4 + 1] = v.y;
            xv[i * 4 + 2] = v.z; xv[i * 4 + 3] = v.w;
        }
        float sumsq = 0.f;
#pragma unroll
        for (int i = 0; i < 16; ++i) sumsq += xv[i] * xv[i];
        float p = 0.f;
#pragma unroll
        for (int jj = 0; jj < 2; ++jj) {
            const int j = jg + jj * 8;
            float y = 0.f;
#pragma unroll
            for (int i = 0; i < 16; ++i) {
                float mv = net[r * NSTR + ((i * (i + 1)) >> 1) + j];
                y += (i >= j) ? mv * xv[i] : 0.f;
            }
            p += y * y;
        }
        p += __shfl_xor(p, 1);
        p += __shfl_xor(p, 2);
        p += __shfl_xor(p, 4);
        if (jg == 0) out[row0 + r] = p + 1e-6f * sumsq;
    }
}

extern "C" void kernel_launch(void* const* d_in, const int* in_sizes, int n_in,
                              void* d_out, int out_size, void* d_ws, size_t ws_size,
                              hipStream_t stream) {
    const float* points = (const float*)d_in[0];
    const float* W0 = (const float*)d_in[1];
    const float* b0 = (const float*)d_in[2];
    const float* W1 = (const float*)d_in[3];
    const float* b1 = (const float*)d_in[4];
    const float* W2 = (const float*)d_in[5];
    const float* b2 = (const float*)d_in[6];
    __bf16* ws = (__bf16*)d_ws;
    float* out = (float*)d_out;

    prep_weights<<<86, 512, 0, stream>>>(W0, W1, W2, ws);

    const int B = in_sizes[0] / 16;   // 131072
    fused_mlp_quad<<<B / 64, 512, 0, stream>>>(points, b0, b1, b2, ws, out);
}

// Round 9
// 195.290 us; speedup vs baseline: 1.0996x; 1.0014x over previous
//
#include <hip/hip_runtime.h>

typedef __bf16 bf16x4 __attribute__((ext_vector_type(4)));
typedef __bf16 bf16x8 __attribute__((ext_vector_type(8)));
typedef float f32x16 __attribute__((ext_vector_type(16)));

#define TC 2.885390081777926f   // 2/ln2, folded into W0/W1 at prep

// ---- workspace layout (bf16 element offsets), FRAGMENT-ORDERED weights ----
// 1 KB record per (nt,kk): elem (lane,j) at rec*512 + lane*8 + j
//   n = nt*32 + (lane&31), k = kk*16 + (lane>>5)*8 + j
// W0: recs [0,16). W1: rep copies, recs [16, 16+rep*512). W2: recs after.
#define W0F_OFF 0
#define W1F_OFF 8192              // elements
#define W1SZ    262144            // elements per W1 copy (512 recs)

// One wave per 1KB record: coalesced row reads, coalesced dwordx4 stores.
// W0/W1 pre-scaled by TC. W1 written rep times (R26: L2 requester dilution).
__global__ void prep_weights(const float* __restrict__ W0,
                             const float* __restrict__ W1,
                             const float* __restrict__ W2,
                             __bf16* __restrict__ ws, int rep) {
    const int wave = blockIdx.x * 8 + (threadIdx.x >> 6);
    const int l   = threadIdx.x & 63;
    const int col = l & 31, kh = l >> 5;
    const int nW1 = rep * 512;
    const float* src; int nt, kk, S, nlim; float scl;
    if (wave < 16)            { src = W0; nt = wave; kk = 0; S = 512; nlim = 512; scl = TC; }
    else if (wave < 16 + nW1) { int r = (wave - 16) & 511;  src = W1; nt = r >> 5; kk = r & 31; S = 512; nlim = 512; scl = TC; }
    else                      { int r = wave - 16 - nW1;    src = W2; nt = r >> 5; kk = r & 31; S = 136; nlim = 136; scl = 1.0f; }
    const int n  = nt * 32 + col;
    const int k0 = kk * 16 + kh * 8;
    bf16x8 v;
#pragma unroll
    for (int j = 0; j < 8; ++j)
        v[j] = (n < nlim) ? (__bf16)(src[(k0 + j) * S + n] * scl) : (__bf16)0.0f;
    *(bf16x8*)(ws + (long)wave * 512 + l * 8) = v;
}

// input y is pre-scaled by TC: tanh(x) = 1 - 2/(exp2(TC*x)+1)
__device__ __forceinline__ float fast_tanh_pre(float y) {
#if __has_builtin(__builtin_amdgcn_exp2f)
    float e = __builtin_amdgcn_exp2f(y);
#else
    float e = exp2f(y);
#endif
    return 1.0f - 2.0f * __builtin_amdgcn_rcpf(e + 1.0f);
}

// h LDS: [64][520] bf16 (rows 1040 B, 16B-aligned), ds_read_b128.
#define HSTR 520
// net LDS: [64][140] f32 overlay (float4-aligned rows).
#define NSTR 140

// R26 = R17 core (136.6us proven; swizzle REVERTED: R25 showed 6x conflicts +
// 4us VALU with ZERO time change -> conflicts & VALU off critical path) +
// coalesced prep + TC-folded weights + W1 REPLICATION. Evidence chain:
// - six scheduling nulls + conflict null: no pipe quantity moves wall time
//   at the margin -> latency-bound, not throughput-bound.
// - the only positive result ever (K-rotation, 142->136.6) de-phased the
//   shared-W1 L2 stream -> L2 contention is the live suspect.
// - mechanism: 32 CUs/XCD demand the SAME W1 line near-simultaneously; L2
//   port serializes ~32 requesters -> effective latency >> the ~774 cyc that
//   3 partner-waves of MFMA can cover.
// Fix: rep in {8,4,1} physical W1 copies (ws_size-guarded); block uses copy
// (blockIdx>>3)&(rep-1) so co-XCD blocks hit DIFFERENT copies: requesters/
// line 32 -> 32/rep; per-XCD L2 footprint rep*512KB <= 4MB.
// Predictions: VGPR 56-64, WRITE~512KB, conflicts ~2.6M; if L2-contention
// theory right dur -> 110-125us; null 135-139 -> declare structural ceiling.
__global__ __launch_bounds__(512, 2)
void fused_mlp_quad(const float* __restrict__ points,
                    const float* __restrict__ b0,
                    const float* __restrict__ b1,
                    const float* __restrict__ b2,
                    const __bf16* __restrict__ ws,
                    float* __restrict__ out, int rep) {
    __shared__ __align__(16) unsigned char lds_raw[66560];
    __bf16* h  = (__bf16*)lds_raw;   // [64][HSTR] bf16 (h0, then h1 in place)
    float* net = (float*)lds_raw;    // [64][NSTR] f32 overlay after phase 2

    const __bf16* w0f = ws + W0F_OFF;
    // Copy selection: co-XCD-resident blocks (same blockIdx&7 ring position,
    // different >>3 group) pick different copies -> per-line requester dilution.
    const __bf16* w1f = ws + W1F_OFF + (long)((blockIdx.x >> 3) & (rep - 1)) * W1SZ;
    const __bf16* w2f = ws + W1F_OFF + (long)rep * W1SZ;

    const int tid = threadIdx.x;
    const int w   = tid >> 6;     // wave 0..7
    const int l   = tid & 63;
    const int ln  = l & 31;       // batch row within tile / 32x32 lane index
    const int hi  = l >> 5;       // k-half
    const int row0 = blockIdx.x * 64;

    const int lofs = l * 8;       // lane offset within a 1KB fragment record
    const int ofs16 = (blockIdx.x >> 3) & 15;   // K-rotation (16-way per XCD)
    const int ofs8  = (blockIdx.x >> 3) & 7;

    // ---------- phase 0: h0 = tanh(x @ W0' + TC*b0), K=16 = one MFMA step ----------
    {
        bf16x8 bx[2];
#pragma unroll
        for (int bt = 0; bt < 2; ++bt) {
            const float* src = points + (row0 + bt * 32 + ln) * 16 + hi * 8;
            float4 p0 = ((const float4*)src)[0];
            float4 p1 = ((const float4*)src)[1];
            bf16x8 v;
            v[0] = (__bf16)p0.x; v[1] = (__bf16)p0.y; v[2] = (__bf16)p0.z; v[3] = (__bf16)p0.w;
            v[4] = (__bf16)p1.x; v[5] = (__bf16)p1.y; v[6] = (__bf16)p1.z; v[7] = (__bf16)p1.w;
            bx[bt] = v;
        }
#pragma unroll
        for (int t = 0; t < 2; ++t) {
            const int ntg = w * 2 + t;
            bf16x8 wf = *(const bf16x8*)(w0f + ntg * 512 + lofs);
#pragma unroll
            for (int bt = 0; bt < 2; ++bt) {
                f32x16 acc = {};
                acc = __builtin_amdgcn_mfma_f32_32x32x16_bf16(wf, bx[bt], acc, 0, 0, 0);
#pragma unroll
                for (int rg = 0; rg < 4; ++rg) {
                    const int n0 = ntg * 32 + 8 * rg + 4 * hi;
                    float4 bias = *(const float4*)(b0 + n0);
                    bf16x4 v;
                    v[0] = (__bf16)fast_tanh_pre(fmaf(TC, bias.x, acc[4 * rg + 0]));
                    v[1] = (__bf16)fast_tanh_pre(fmaf(TC, bias.y, acc[4 * rg + 1]));
                    v[2] = (__bf16)fast_tanh_pre(fmaf(TC, bias.z, acc[4 * rg + 2]));
                    v[3] = (__bf16)fast_tanh_pre(fmaf(TC, bias.w, acc[4 * rg + 3]));
                    *(bf16x4*)(h + (bt * 32 + ln) * HSTR + n0) = v;
                }
            }
        }
    }
    __syncthreads();

    // ---------- phase 1: h1 = tanh(h0 @ W1' + TC*b1) ----------
    // wave: 2 nt x 2 bt; acc = 64 AGPR. Batch-2 super-iters, ROTATED start.
    f32x16 acc1[2][2] = {};   // [bt][t]
    {
        const __bf16* arow0 = h + ln * HSTR + hi * 8;          // bt=0
        const __bf16* arow1 = h + (32 + ln) * HSTR + hi * 8;   // bt=1
        const __bf16* wb0 = w1f + (w * 2 + 0) * 16384 + lofs;
        const __bf16* wb1 = w1f + (w * 2 + 1) * 16384 + lofs;
        for (int ks2 = 0; ks2 < 16; ++ks2) {
            const int ks = (ks2 + ofs16) & 15;   // block-dependent rotation
            bf16x8 aa[2][2], bb[2][2];
#pragma unroll
            for (int u = 0; u < 2; ++u) {
                const int kk = ks * 2 + u;
                const int vo = kk * 512;
                aa[u][0] = *(const bf16x8*)(arow0 + kk * 16);
                aa[u][1] = *(const bf16x8*)(arow1 + kk * 16);
                bb[u][0] = *(const bf16x8*)(wb0 + vo);
                bb[u][1] = *(const bf16x8*)(wb1 + vo);
            }
#pragma unroll
            for (int u = 0; u < 2; ++u) {
#pragma unroll
                for (int t = 0; t < 2; ++t) {
                    acc1[0][t] = __builtin_amdgcn_mfma_f32_32x32x16_bf16(bb[u][t], aa[u][0], acc1[0][t], 0, 0, 0);
                    acc1[1][t] = __builtin_amdgcn_mfma_f32_32x32x16_bf16(bb[u][t], aa[u][1], acc1[1][t], 0, 0, 0);
                }
            }
        }
    }
    __syncthreads();   // all h0 reads done; overwrite in place
#pragma unroll
    for (int t = 0; t < 2; ++t) {
#pragma unroll
        for (int bt = 0; bt < 2; ++bt) {
#pragma unroll
            for (int rg = 0; rg < 4; ++rg) {
                const int n0 = (w * 2 + t) * 32 + 8 * rg + 4 * hi;
                float4 bias = *(const float4*)(b1 + n0);
                bf16x4 v;
                v[0] = (__bf16)fast_tanh_pre(fmaf(TC, bias.x, acc1[bt][t][4 * rg + 0]));
                v[1] = (__bf16)fast_tanh_pre(fmaf(TC, bias.y, acc1[bt][t][4 * rg + 1]));
                v[2] = (__bf16)fast_tanh_pre(fmaf(TC, bias.z, acc1[bt][t][4 * rg + 2]));
                v[3] = (__bf16)fast_tanh_pre(fmaf(TC, bias.w, acc1[bt][t][4 * rg + 3]));
                *(bf16x4*)(h + (bt * 32 + ln) * HSTR + n0) = v;
            }
        }
    }
    __syncthreads();

    // ---------- phase 2: net = h1 @ W2 + b2 (N pad 160: 5 nt x 2 bt = 10 tiles) ----
    // wave w: tile (nt = w>>1, bt = w&1); waves 0,1 also tile (nt=4, bt=w).
    f32x16 acc2a = {}, acc2e = {};
    const int nt2 = w >> 1;
    const int bt2 = w & 1;
    const bool two = (w < 2);
    {
        const __bf16* arowA = h + (bt2 * 32 + ln) * HSTR + hi * 8;
        const __bf16* arowE = h + ((w & 1) * 32 + ln) * HSTR + hi * 8;  // bt=w for w<2
        const __bf16* wbA = w2f + nt2 * 16384 + lofs;
        const __bf16* wbE = w2f + 4 * 16384 + lofs;
        for (int ks2 = 0; ks2 < 8; ++ks2) {
            const int ks = (ks2 + ofs8) & 7;     // block-dependent rotation
            bf16x8 aaA[2], wA[2], aaE[2], wE[2];
#pragma unroll
            for (int u = 0; u < 2; ++u) {
                const int kk = ks * 4 + u * 2;   // two kk per u-step (batch-2 of pairs)
                const int vo = kk * 512;
                aaA[u] = *(const bf16x8*)(arowA + kk * 16);
                wA[u]  = *(const bf16x8*)(wbA + vo);
                if (two) {
                    aaE[u] = *(const bf16x8*)(arowE + kk * 16);
                    wE[u]  = *(const bf16x8*)(wbE + vo);
                }
            }
            bf16x8 aaA2[2], wA2[2], aaE2[2], wE2[2];
#pragma unroll
            for (int u = 0; u < 2; ++u) {
                const int kk = ks * 4 + u * 2 + 1;
                const int vo = kk * 512;
                aaA2[u] = *(const bf16x8*)(arowA + kk * 16);
                wA2[u]  = *(const bf16x8*)(wbA + vo);
                if (two) {
                    aaE2[u] = *(const bf16x8*)(arowE + kk * 16);
                    wE2[u]  = *(const bf16x8*)(wbE + vo);
                }
            }
#pragma unroll
            for (int u = 0; u < 2; ++u) {
                acc2a = __builtin_amdgcn_mfma_f32_32x32x16_bf16(wA[u], aaA[u], acc2a, 0, 0, 0);
                acc2a = __builtin_amdgcn_mfma_f32_32x32x16_bf16(wA2[u], aaA2[u], acc2a, 0, 0, 0);
                if (two) {
                    acc2e = __builtin_amdgcn_mfma_f32_32x32x16_bf16(wE[u], aaE[u], acc2e, 0, 0, 0);
                    acc2e = __builtin_amdgcn_mfma_f32_32x32x16_bf16(wE2[u], aaE2[u], acc2e, 0, 0, 0);
                }
            }
        }
    }
    __syncthreads();   // all h1 reads done; overwrite with net (fp32)
    {
#pragma unroll
        for (int rg = 0; rg < 4; ++rg) {
            const int n0 = nt2 * 32 + 8 * rg + 4 * hi;   // <= 127 < 136
            float4 bias = *(const float4*)(b2 + n0);
            float4 v;
            v.x = acc2a[4 * rg + 0] + bias.x;
            v.y = acc2a[4 * rg + 1] + bias.y;
            v.z = acc2a[4 * rg + 2] + bias.z;
            v.w = acc2a[4 * rg + 3] + bias.w;
            *(float4*)(net + (bt2 * 32 + ln) * NSTR + n0) = v;
        }
        if (two) {
            // extra tile nt=4 (n 128..135): only rg==0 in range (n0=128/132)
            const int n0 = 128 + 4 * hi;
            float4 bias = *(const float4*)(b2 + n0);
            float4 v;
            v.x = acc2e[0] + bias.x;
            v.y = acc2e[1] + bias.y;
            v.z = acc2e[2] + bias.z;
            v.w = acc2e[3] + bias.w;
            *(float4*)(net + ((w & 1) * 32 + ln) * NSTR + n0) = v;
        }
    }
    __syncthreads();

    // ---------- phase 3: vals = ||M^T x||^2 + eps*||x||^2 ----------
    // 8 threads per row x 64 rows = 512 threads, single pass
    {
        const int r  = tid >> 3;
        const int jg = tid & 7;
        const float* xp = points + (row0 + r) * 16;
        float xv[16];
#pragma unroll
        for (int i = 0; i < 4; ++i) {
            float4 v = ((const float4*)xp)[i];
            xv[i * 4 + 0] = v.x; xv[i * 4 + 1] = v.y;
            xv[i * 4 + 2] = v.z; xv[i * 4 + 3] = v.w;
        }
        float sumsq = 0.f;
#pragma unroll
        for (int i = 0; i < 16; ++i) sumsq += xv[i] * xv[i];
        float p = 0.f;
#pragma unroll
        for (int jj = 0; jj < 2; ++jj) {
            const int j = jg + jj * 8;
            float y = 0.f;
#pragma unroll
            for (int i = 0; i < 16; ++i) {
                float mv = net[r * NSTR + ((i * (i + 1)) >> 1) + j];
                y += (i >= j) ? mv * xv[i] : 0.f;
            }
            p += y * y;
        }
        p += __shfl_xor(p, 1);
        p += __shfl_xor(p, 2);
        p += __shfl_xor(p, 4);
        if (jg == 0) out[row0 + r] = p + 1e-6f * sumsq;
    }
}

extern "C" void kernel_launch(void* const* d_in, const int* in_sizes, int n_in,
                              void* d_out, int out_size, void* d_ws, size_t ws_size,
                              hipStream_t stream) {
    const float* points = (const float*)d_in[0];
    const float* W0 = (const float*)d_in[1];
    const float* b0 = (const float*)d_in[2];
    const float* W1 = (const float*)d_in[3];
    const float* b1 = (const float*)d_in[4];
    const float* W2 = (const float*)d_in[5];
    const float* b2 = (const float*)d_in[6];
    __bf16* ws = (__bf16*)d_ws;
    float* out = (float*)d_out;

    // rep = W1 replication factor (power of 2), guarded by workspace size.
    // bytes(rep) = (8192 + rep*262144 + 81920) * 2
    int rep = 1;
    if (ws_size >= (size_t)(8192 + 8 * W1SZ + 81920) * 2) rep = 8;
    else if (ws_size >= (size_t)(8192 + 4 * W1SZ + 81920) * 2) rep = 4;
    else if (ws_size >= (size_t)(8192 + 2 * W1SZ + 81920) * 2) rep = 2;

    const int prep_waves = 16 + rep * 512 + 160;   // divisible by 8
    prep_weights<<<prep_waves / 8, 512, 0, stream>>>(W0, W1, W2, ws, rep);

    const int B = in_sizes[0] / 16;   // 131072
    fused_mlp_quad<<<B / 64, 512, 0, stream>>>(points, b0, b1, b2, ws, out, rep);
}